// Round 3
// baseline (1412.700 us; speedup 1.0000x reference)
//
#include <hip/hip_runtime.h>

#define N_NODES 20000
#define N_EDGES 640000
#define FDIM 64
#define NB 20
#define LN_EPS 1e-5f
#define EPW 8          // edges per wave per iteration

__device__ __forceinline__ float silu_f(float x) {
    return x / (1.0f + __expf(-x));
}

// ---------------- Kernel A: node MLP  mn = silu(atom@W1+b1)@W2+b2 (persistent) ----------------
__global__ __launch_bounds__(256) void node_mlp_kernel(
    const float* __restrict__ atom, const float* __restrict__ W1, const float* __restrict__ b1,
    const float* __restrict__ W2, const float* __restrict__ b2, float* __restrict__ mn)
{
    __shared__ float W1s[FDIM][FDIM];
    __shared__ float W2s[FDIM][FDIM];
    __shared__ float rowS[4][FDIM];
    __shared__ float hidS[4][FDIM];
    const int f = threadIdx.x, ty = threadIdx.y;
    const int tid = ty * 64 + f;
    for (int i = tid; i < FDIM * FDIM; i += 256) {
        ((float*)W1s)[i] = W1[i];
        ((float*)W2s)[i] = W2[i];
    }
    __syncthreads();
    const float bb1 = b1[f], bb2 = b2[f];
    const int nw = gridDim.x * 4;
    for (int n = blockIdx.x * 4 + ty; n < N_NODES; n += nw) {
        rowS[ty][f] = atom[n * FDIM + f];          // wave-local, no barrier needed
        float h = bb1;
#pragma unroll
        for (int g = 0; g < FDIM; g += 4) {
            float4 a4 = *(const float4*)&rowS[ty][g];
            h += a4.x * W1s[g + 0][f] + a4.y * W1s[g + 1][f]
               + a4.z * W1s[g + 2][f] + a4.w * W1s[g + 3][f];
        }
        h = silu_f(h);
        hidS[ty][f] = h;
        float o = bb2;
#pragma unroll
        for (int g = 0; g < FDIM; g += 4) {
            float4 a4 = *(const float4*)&hidS[ty][g];
            o += a4.x * W2s[g + 0][f] + a4.y * W2s[g + 1][f]
               + a4.z * W2s[g + 2][f] + a4.w * W2s[g + 3][f];
        }
        mn[n * FDIM + f] = o;
    }
}

// ---------------- Kernel B: per-edge pipeline (persistent, 8 waves/block, EPW edges/wave) ------
// LDS = 4 weight matrices (64 KB) + ONE reused staging buffer (16 KB) = 80 KB -> 2 blocks/CU.
// The staging buffer is wave-local and reused sequentially (msg -> h1 -> h2); DS ops from a
// single wave execute in order, so no barriers are required after the initial weight load.
__global__ __launch_bounds__(512) void edge_kernel(
    const float* __restrict__ dist,   // [E,20]
    const float* __restrict__ dir,    // [E,3]
    const int* __restrict__ eidx,     // [2,E] int32
    const float* __restrict__ mn,     // [N,F]
    const float* __restrict__ We,     // [20,F]
    const float* __restrict__ Wq1a, const float* __restrict__ Wq1b,
    const float* __restrict__ Wq2a, const float* __restrict__ Wq2b,
    const float* __restrict__ forceN, // [N,3,F] original force_node
    float* __restrict__ atomAcc,      // [N,F]
    float* __restrict__ forceAcc)     // [N,3,F]
{
    __shared__ float Aq1[FDIM][FDIM], Bq1[FDIM][FDIM];
    __shared__ float Aq2[FDIM][FDIM], Bq2[FDIM][FDIM];
    __shared__ float sS[8][EPW][FDIM];   // reused: msg -> h1 -> h2
    const int f = threadIdx.x, ty = threadIdx.y;   // ty in 0..7
    const int tid = ty * 64 + f;
    for (int i = tid; i < FDIM * FDIM; i += 512) {
        ((float*)Aq1)[i] = Wq1a[i];
        ((float*)Bq1)[i] = Wq1b[i];
        ((float*)Aq2)[i] = Wq2a[i];
        ((float*)Bq2)[i] = Wq2b[i];
    }
    __syncthreads();   // only barrier in the kernel

    float we[NB];
#pragma unroll
    for (int b = 0; b < NB; ++b) we[b] = We[b * FDIM + f];

    const int ngroups = N_EDGES / EPW;
    const int stride = gridDim.x * 8;
    for (int grp = blockIdx.x * 8 + ty; grp < ngroups; grp += stride) {
        const int e0 = grp * EPW;
        int srcs[EPW], dsts[EPW];
#pragma unroll
        for (int j = 0; j < EPW; ++j) {
            srcs[j] = __builtin_amdgcn_readfirstlane(eidx[e0 + j]);
            dsts[j] = __builtin_amdgcn_readfirstlane(eidx[N_EDGES + e0 + j]);
        }
        // message = (dist@We) * mn[src] * mn[dst]; scatter to atomAcc; stage in wave-local LDS
#pragma unroll
        for (int j = 0; j < EPW; ++j) {
            float me = 0.0f;
#pragma unroll
            for (int b = 0; b < NB; ++b) me += dist[(e0 + j) * NB + b] * we[b];
            const float m = me * mn[srcs[j] * FDIM + f] * mn[dsts[j] * FDIM + f];
            atomicAdd(&atomAcc[srcs[j] * FDIM + f], m);
            sS[ty][j][f] = m;
        }
        // h1 = silu(msg@Wq1a), h2 = silu(msg@Wq2a)
        float h1[EPW], h2[EPW];
#pragma unroll
        for (int j = 0; j < EPW; ++j) { h1[j] = 0.0f; h2[j] = 0.0f; }
#pragma unroll
        for (int g = 0; g < FDIM; g += 4) {
            const float w1a = Aq1[g][f], w1b = Aq1[g + 1][f], w1c = Aq1[g + 2][f], w1d = Aq1[g + 3][f];
            const float w2a = Aq2[g][f], w2b = Aq2[g + 1][f], w2c = Aq2[g + 2][f], w2d = Aq2[g + 3][f];
#pragma unroll
            for (int j = 0; j < EPW; ++j) {
                float4 m4 = *(const float4*)&sS[ty][j][g];
                h1[j] += m4.x * w1a + m4.y * w1b + m4.z * w1c + m4.w * w1d;
                h2[j] += m4.x * w2a + m4.y * w2b + m4.z * w2c + m4.w * w2d;
            }
        }
        // stage h1 (msg fully consumed above; same-wave DS in-order keeps this safe)
#pragma unroll
        for (int j = 0; j < EPW; ++j) {
            h1[j] = silu_f(h1[j]);
            h2[j] = silu_f(h2[j]);
            sS[ty][j][f] = h1[j];
        }
        // e1 = h1@Wq1b
        float e1[EPW], e2[EPW];
#pragma unroll
        for (int j = 0; j < EPW; ++j) { e1[j] = 0.0f; e2[j] = 0.0f; }
#pragma unroll
        for (int g = 0; g < FDIM; g += 4) {
            const float v1a = Bq1[g][f], v1b = Bq1[g + 1][f], v1c = Bq1[g + 2][f], v1d = Bq1[g + 3][f];
#pragma unroll
            for (int j = 0; j < EPW; ++j) {
                float4 a4 = *(const float4*)&sS[ty][j][g];
                e1[j] += a4.x * v1a + a4.y * v1b + a4.z * v1c + a4.w * v1d;
            }
        }
        // stage h2 (h1 fully consumed above)
#pragma unroll
        for (int j = 0; j < EPW; ++j) sS[ty][j][f] = h2[j];
        // e2 = h2@Wq2b
#pragma unroll
        for (int g = 0; g < FDIM; g += 4) {
            const float v2a = Bq2[g][f], v2b = Bq2[g + 1][f], v2c = Bq2[g + 2][f], v2d = Bq2[g + 3][f];
#pragma unroll
            for (int j = 0; j < EPW; ++j) {
                float4 b4 = *(const float4*)&sS[ty][j][g];
                e2[j] += b4.x * v2a + b4.y * v2b + b4.z * v2c + b4.w * v2d;
            }
        }
        // equivariant scatter
#pragma unroll
        for (int j = 0; j < EPW; ++j) {
            const float d0 = dir[(e0 + j) * 3 + 0];
            const float d1 = dir[(e0 + j) * 3 + 1];
            const float d2 = dir[(e0 + j) * 3 + 2];
            const float* fd = forceN + (size_t)dsts[j] * 3 * FDIM;
            float* fa = forceAcc + (size_t)srcs[j] * 3 * FDIM;
            atomicAdd(&fa[0 * FDIM + f], e1[j] * d0 + e2[j] * fd[0 * FDIM + f]);
            atomicAdd(&fa[1 * FDIM + f], e1[j] * d1 + e2[j] * fd[1 * FDIM + f]);
            atomicAdd(&fa[2 * FDIM + f], e1[j] * d2 + e2[j] * fd[2 * FDIM + f]);
        }
    }
}

// ---------------- Kernel C: finalize nodes (inv_update2 + LayerNorm, persistent) ----------------
__global__ __launch_bounds__(256) void node_final_kernel(
    const float* __restrict__ Wu, const float* __restrict__ gamma, const float* __restrict__ beta,
    float* __restrict__ atomAcc,        // [N,F]
    const float* __restrict__ forceOut) // [N,3,F]
{
    __shared__ float Wus[FDIM][FDIM];
    __shared__ float fS[4][3][FDIM];
    const int f = threadIdx.x, ty = threadIdx.y;
    const int tid = ty * 64 + f;
    for (int i = tid; i < FDIM * FDIM; i += 256) ((float*)Wus)[i] = Wu[i];
    __syncthreads();
    const float gg = gamma[f], bb = beta[f];
    const int nw = gridDim.x * 4;
    for (int n = blockIdx.x * 4 + ty; n < N_NODES; n += nw) {
        const float f0 = forceOut[((size_t)n * 3 + 0) * FDIM + f];
        const float f1 = forceOut[((size_t)n * 3 + 1) * FDIM + f];
        const float f2 = forceOut[((size_t)n * 3 + 2) * FDIM + f];
        fS[ty][0][f] = f0;
        fS[ty][1][f] = f1;
        fS[ty][2][f] = f2;
        float r0 = 0.0f, r1 = 0.0f, r2 = 0.0f;
#pragma unroll
        for (int g = 0; g < FDIM; g += 4) {
            float4 a0 = *(const float4*)&fS[ty][0][g];
            float4 a1 = *(const float4*)&fS[ty][1][g];
            float4 a2 = *(const float4*)&fS[ty][2][g];
            const float wa = Wus[g + 0][f], wb = Wus[g + 1][f], wc = Wus[g + 2][f], wd = Wus[g + 3][f];
            r0 += a0.x * wa + a0.y * wb + a0.z * wc + a0.w * wd;
            r1 += a1.x * wa + a1.y * wb + a1.z * wc + a1.w * wd;
            r2 += a2.x * wa + a2.y * wb + a2.z * wc + a2.w * wd;
        }
        float a = atomAcc[n * FDIM + f] + (f0 * r0 + f1 * r1 + f2 * r2);
        float s = a;
#pragma unroll
        for (int off = 32; off >= 1; off >>= 1) s += __shfl_xor(s, off, 64);
        const float mu = s * (1.0f / 64.0f);
        const float d = a - mu;
        float v = d * d;
#pragma unroll
        for (int off = 32; off >= 1; off >>= 1) v += __shfl_xor(v, off, 64);
        v *= (1.0f / 64.0f);
        atomAcc[n * FDIM + f] = d * rsqrtf(v + LN_EPS) * gg + bb;
    }
}

extern "C" void kernel_launch(void* const* d_in, const int* in_sizes, int n_in,
                              void* d_out, int out_size, void* d_ws, size_t ws_size,
                              hipStream_t stream)
{
    const float* atom_node  = (const float*)d_in[0];
    const float* force_node = (const float*)d_in[1];
    const float* dir_edge   = (const float*)d_in[2];
    const float* dist_edge  = (const float*)d_in[3];
    const int*   edge_index = (const int*)d_in[4];
    const float* W1   = (const float*)d_in[5];
    const float* b1   = (const float*)d_in[6];
    const float* W2   = (const float*)d_in[7];
    const float* b2   = (const float*)d_in[8];
    const float* We   = (const float*)d_in[9];
    const float* Wq1a = (const float*)d_in[10];
    const float* Wq1b = (const float*)d_in[11];
    const float* Wq2a = (const float*)d_in[12];
    const float* Wq2b = (const float*)d_in[13];
    const float* Wu   = (const float*)d_in[14];
    const float* gamma = (const float*)d_in[15];
    const float* beta  = (const float*)d_in[16];

    float* atomOut  = (float*)d_out;                          // [N,F]
    float* forceOut = (float*)d_out + (size_t)N_NODES * FDIM; // [N,3,F]
    float* mn = (float*)d_ws;                                 // [N,F] scratch

    hipMemcpyAsync(atomOut, atom_node, (size_t)N_NODES * FDIM * sizeof(float),
                   hipMemcpyDeviceToDevice, stream);
    hipMemcpyAsync(forceOut, force_node, (size_t)N_NODES * 3 * FDIM * sizeof(float),
                   hipMemcpyDeviceToDevice, stream);

    dim3 blk4(64, 4);
    dim3 blk8(64, 8);
    node_mlp_kernel<<<512, blk4, 0, stream>>>(atom_node, W1, b1, W2, b2, mn);
    edge_kernel<<<512, blk8, 0, stream>>>(dist_edge, dir_edge, edge_index, mn, We,
                                          Wq1a, Wq1b, Wq2a, Wq2b, force_node,
                                          atomOut, forceOut);
    node_final_kernel<<<512, blk4, 0, stream>>>(Wu, gamma, beta, atomOut, forceOut);
}

// Round 4
// 907.124 us; speedup vs baseline: 1.5573x; 1.5573x over previous
//
#include <hip/hip_runtime.h>

#define N_NODES 20000
#define N_EDGES 640000
#define FDIM 64
#define NB 20
#define LN_EPS 1e-5f
#define EPW 8          // edges per wave per iteration

__device__ __forceinline__ float silu_f(float x) {
    return x / (1.0f + __expf(-x));
}

__device__ __forceinline__ float bcast_lane(float v, int lane) {
    return __int_as_float(__builtin_amdgcn_readlane(__float_as_int(v), lane));
}

// ---------------- Kernel A: node MLP  mn = silu(atom@W1+b1)@W2+b2 (persistent) ----------------
__global__ __launch_bounds__(256) void node_mlp_kernel(
    const float* __restrict__ atom, const float* __restrict__ W1, const float* __restrict__ b1,
    const float* __restrict__ W2, const float* __restrict__ b2, float* __restrict__ mn)
{
    __shared__ float W1s[FDIM][FDIM];
    __shared__ float W2s[FDIM][FDIM];
    const int f = threadIdx.x, ty = threadIdx.y;
    const int tid = ty * 64 + f;
    for (int i = tid; i < FDIM * FDIM; i += 256) {
        ((float*)W1s)[i] = W1[i];
        ((float*)W2s)[i] = W2[i];
    }
    __syncthreads();
    const float bb1 = b1[f], bb2 = b2[f];
    const int nw = gridDim.x * 4;
    for (int n = blockIdx.x * 4 + ty; n < N_NODES; n += nw) {
        const float a = atom[n * FDIM + f];
        float h = bb1;
        for (int g = 0; g < FDIM; ++g)
            h += bcast_lane(a, g) * W1s[g][f];
        h = silu_f(h);
        float o = bb2;
        for (int g = 0; g < FDIM; ++g)
            o += bcast_lane(h, g) * W2s[g][f];
        mn[n * FDIM + f] = o;
    }
}

// ---------------- Kernel B: per-edge pipeline (persistent, readlane broadcast matmuls) ---------
// LDS holds ONLY the 4 weight matrices (64 KB). All msg/h1/h2 broadcasts are done in-register
// via v_readlane (VALU pipe, per-SIMD parallel) instead of LDS b128 broadcasts (shared pipe).
__global__ __launch_bounds__(512, 4) void edge_kernel(
    const float* __restrict__ dist,   // [E,20]
    const float* __restrict__ dir,    // [E,3]
    const int* __restrict__ eidx,     // [2,E] int32
    const float* __restrict__ mn,     // [N,F]
    const float* __restrict__ We,     // [20,F]
    const float* __restrict__ Wq1a, const float* __restrict__ Wq1b,
    const float* __restrict__ Wq2a, const float* __restrict__ Wq2b,
    const float* __restrict__ forceN, // [N,3,F] original force_node
    float* __restrict__ atomAcc,      // [N,F]
    float* __restrict__ forceAcc)     // [N,3,F]
{
    __shared__ float Aq1[FDIM][FDIM], Bq1[FDIM][FDIM];
    __shared__ float Aq2[FDIM][FDIM], Bq2[FDIM][FDIM];
    const int f = threadIdx.x, ty = threadIdx.y;   // ty in 0..7
    const int tid = ty * 64 + f;
    for (int i = tid; i < FDIM * FDIM; i += 512) {
        ((float*)Aq1)[i] = Wq1a[i];
        ((float*)Bq1)[i] = Wq1b[i];
        ((float*)Aq2)[i] = Wq2a[i];
        ((float*)Bq2)[i] = Wq2b[i];
    }
    __syncthreads();   // only barrier in the kernel

    float we[NB];
#pragma unroll
    for (int b = 0; b < NB; ++b) we[b] = We[b * FDIM + f];

    const int ngroups = N_EDGES / EPW;
    const int stride = gridDim.x * 8;
    for (int grp = blockIdx.x * 8 + ty; grp < ngroups; grp += stride) {
        const int e0 = grp * EPW;
        int srcs[EPW], dsts[EPW];
#pragma unroll
        for (int j = 0; j < EPW; ++j) {
            srcs[j] = __builtin_amdgcn_readfirstlane(eidx[e0 + j]);
            dsts[j] = __builtin_amdgcn_readfirstlane(eidx[N_EDGES + e0 + j]);
        }
        // message = (dist@We) * mn[src] * mn[dst]; scatter-add to atomAcc; keep in registers
        float msg[EPW];
#pragma unroll
        for (int j = 0; j < EPW; ++j) {
            float me = 0.0f;
#pragma unroll
            for (int b = 0; b < NB; ++b) me += dist[(e0 + j) * NB + b] * we[b];
            msg[j] = me * mn[srcs[j] * FDIM + f] * mn[dsts[j] * FDIM + f];
            atomicAdd(&atomAcc[srcs[j] * FDIM + f], msg[j]);
        }
        // h1 = silu(msg@Wq1a), h2 = silu(msg@Wq2a) — msg[g] broadcast via readlane
        float h1[EPW], h2[EPW];
#pragma unroll
        for (int j = 0; j < EPW; ++j) { h1[j] = 0.0f; h2[j] = 0.0f; }
#pragma unroll 8
        for (int g = 0; g < FDIM; ++g) {
            const float w1 = Aq1[g][f];
            const float w2 = Aq2[g][f];
#pragma unroll
            for (int j = 0; j < EPW; ++j) {
                const float s = bcast_lane(msg[j], g);
                h1[j] += s * w1;
                h2[j] += s * w2;
            }
        }
#pragma unroll
        for (int j = 0; j < EPW; ++j) {
            h1[j] = silu_f(h1[j]);
            h2[j] = silu_f(h2[j]);
        }
        // e1 = h1@Wq1b, e2 = h2@Wq2b — same readlane broadcast
        float e1[EPW], e2[EPW];
#pragma unroll
        for (int j = 0; j < EPW; ++j) { e1[j] = 0.0f; e2[j] = 0.0f; }
#pragma unroll 8
        for (int g = 0; g < FDIM; ++g) {
            const float v1 = Bq1[g][f];
            const float v2 = Bq2[g][f];
#pragma unroll
            for (int j = 0; j < EPW; ++j) {
                e1[j] += bcast_lane(h1[j], g) * v1;
                e2[j] += bcast_lane(h2[j], g) * v2;
            }
        }
        // equivariant scatter
#pragma unroll
        for (int j = 0; j < EPW; ++j) {
            const float d0 = dir[(e0 + j) * 3 + 0];
            const float d1 = dir[(e0 + j) * 3 + 1];
            const float d2 = dir[(e0 + j) * 3 + 2];
            const float* fd = forceN + (size_t)dsts[j] * 3 * FDIM;
            float* fa = forceAcc + (size_t)srcs[j] * 3 * FDIM;
            atomicAdd(&fa[0 * FDIM + f], e1[j] * d0 + e2[j] * fd[0 * FDIM + f]);
            atomicAdd(&fa[1 * FDIM + f], e1[j] * d1 + e2[j] * fd[1 * FDIM + f]);
            atomicAdd(&fa[2 * FDIM + f], e1[j] * d2 + e2[j] * fd[2 * FDIM + f]);
        }
    }
}

// ---------------- Kernel C: finalize nodes (inv_update2 + LayerNorm, persistent) ----------------
__global__ __launch_bounds__(256) void node_final_kernel(
    const float* __restrict__ Wu, const float* __restrict__ gamma, const float* __restrict__ beta,
    float* __restrict__ atomAcc,        // [N,F]
    const float* __restrict__ forceOut) // [N,3,F]
{
    __shared__ float Wus[FDIM][FDIM];
    const int f = threadIdx.x, ty = threadIdx.y;
    const int tid = ty * 64 + f;
    for (int i = tid; i < FDIM * FDIM; i += 256) ((float*)Wus)[i] = Wu[i];
    __syncthreads();
    const float gg = gamma[f], bb = beta[f];
    const int nw = gridDim.x * 4;
    for (int n = blockIdx.x * 4 + ty; n < N_NODES; n += nw) {
        const float f0 = forceOut[((size_t)n * 3 + 0) * FDIM + f];
        const float f1 = forceOut[((size_t)n * 3 + 1) * FDIM + f];
        const float f2 = forceOut[((size_t)n * 3 + 2) * FDIM + f];
        float r0 = 0.0f, r1 = 0.0f, r2 = 0.0f;
#pragma unroll 8
        for (int g = 0; g < FDIM; ++g) {
            const float w = Wus[g][f];
            r0 += bcast_lane(f0, g) * w;
            r1 += bcast_lane(f1, g) * w;
            r2 += bcast_lane(f2, g) * w;
        }
        float a = atomAcc[n * FDIM + f] + (f0 * r0 + f1 * r1 + f2 * r2);
        float s = a;
#pragma unroll
        for (int off = 32; off >= 1; off >>= 1) s += __shfl_xor(s, off, 64);
        const float mu = s * (1.0f / 64.0f);
        const float d = a - mu;
        float v = d * d;
#pragma unroll
        for (int off = 32; off >= 1; off >>= 1) v += __shfl_xor(v, off, 64);
        v *= (1.0f / 64.0f);
        atomAcc[n * FDIM + f] = d * rsqrtf(v + LN_EPS) * gg + bb;
    }
}

extern "C" void kernel_launch(void* const* d_in, const int* in_sizes, int n_in,
                              void* d_out, int out_size, void* d_ws, size_t ws_size,
                              hipStream_t stream)
{
    const float* atom_node  = (const float*)d_in[0];
    const float* force_node = (const float*)d_in[1];
    const float* dir_edge   = (const float*)d_in[2];
    const float* dist_edge  = (const float*)d_in[3];
    const int*   edge_index = (const int*)d_in[4];
    const float* W1   = (const float*)d_in[5];
    const float* b1   = (const float*)d_in[6];
    const float* W2   = (const float*)d_in[7];
    const float* b2   = (const float*)d_in[8];
    const float* We   = (const float*)d_in[9];
    const float* Wq1a = (const float*)d_in[10];
    const float* Wq1b = (const float*)d_in[11];
    const float* Wq2a = (const float*)d_in[12];
    const float* Wq2b = (const float*)d_in[13];
    const float* Wu   = (const float*)d_in[14];
    const float* gamma = (const float*)d_in[15];
    const float* beta  = (const float*)d_in[16];

    float* atomOut  = (float*)d_out;                          // [N,F]
    float* forceOut = (float*)d_out + (size_t)N_NODES * FDIM; // [N,3,F]
    float* mn = (float*)d_ws;                                 // [N,F] scratch

    hipMemcpyAsync(atomOut, atom_node, (size_t)N_NODES * FDIM * sizeof(float),
                   hipMemcpyDeviceToDevice, stream);
    hipMemcpyAsync(forceOut, force_node, (size_t)N_NODES * 3 * FDIM * sizeof(float),
                   hipMemcpyDeviceToDevice, stream);

    dim3 blk4(64, 4);
    dim3 blk8(64, 8);
    node_mlp_kernel<<<512, blk4, 0, stream>>>(atom_node, W1, b1, W2, b2, mn);
    edge_kernel<<<512, blk8, 0, stream>>>(dist_edge, dir_edge, edge_index, mn, We,
                                          Wq1a, Wq1b, Wq2a, Wq2b, force_node,
                                          atomOut, forceOut);
    node_final_kernel<<<512, blk4, 0, stream>>>(Wu, gamma, beta, atomOut, forceOut);
}

// Round 5
// 672.002 us; speedup vs baseline: 2.1022x; 1.3499x over previous
//
#include <hip/hip_runtime.h>

#define N_NODES 20000
#define N_EDGES 640000
#define FDIM 64
#define NB 20
#define LN_EPS 1e-5f

typedef __attribute__((ext_vector_type(8))) short bf16x8;
typedef __attribute__((ext_vector_type(4))) float f32x4;

#define SEL_HI 0x07060302u   // {hi16(s0), hi16(s1)} -> bf16 pair (even k in low half)
#define SEL_LO 0x05040100u   // {lo16(s0), lo16(s1)}
#define MFMA16 __builtin_amdgcn_mfma_f32_16x16x32_bf16

__device__ __forceinline__ float silu_f(float x) { return x / (1.0f + __expf(-x)); }

__device__ __forceinline__ float bcast_lane(float v, int lane) {
    return __int_as_float(__builtin_amdgcn_readlane(__float_as_int(v), lane));
}

__device__ __forceinline__ unsigned bf16_rn(float x) {
    unsigned u = __float_as_uint(x);
    return (u + 0x7FFFu + ((u >> 16) & 1u)) >> 16;
}

// split x into bf16 hi/lo planes, packed (hi<<16)|lo
__device__ __forceinline__ unsigned pack_split(float x) {
    unsigned h = bf16_rn(x);
    unsigned lo = bf16_rn(x - __uint_as_float(h << 16));
    return (h << 16) | lo;
}

// Build A-fragments (hi & lo planes) for one K-half from a staged row of packed u32s.
__device__ __forceinline__ void load_afrag(const unsigned* rowPtr, int kh, int q,
                                           bf16x8* ahi, bf16x8* alo) {
    const uint4 ra = *(const uint4*)(rowPtr + kh * 32 + q * 8);
    const uint4 rb = *(const uint4*)(rowPtr + kh * 32 + q * 8 + 4);
    union { unsigned u[4]; bf16x8 v; } H, L;
    H.u[0] = __builtin_amdgcn_perm(ra.y, ra.x, SEL_HI);
    H.u[1] = __builtin_amdgcn_perm(ra.w, ra.z, SEL_HI);
    H.u[2] = __builtin_amdgcn_perm(rb.y, rb.x, SEL_HI);
    H.u[3] = __builtin_amdgcn_perm(rb.w, rb.z, SEL_HI);
    L.u[0] = __builtin_amdgcn_perm(ra.y, ra.x, SEL_LO);
    L.u[1] = __builtin_amdgcn_perm(ra.w, ra.z, SEL_LO);
    L.u[2] = __builtin_amdgcn_perm(rb.y, rb.x, SEL_LO);
    L.u[3] = __builtin_amdgcn_perm(rb.w, rb.z, SEL_LO);
    *ahi = H.v;
    *alo = L.v;
}

// 3-term fp32-via-bf16 accumulation for one K-half over all 4 N-chunks.
__device__ __forceinline__ void mm3(const unsigned* Bhi, const unsigned* Blo,
                                    bf16x8 ahi, bf16x8 alo, f32x4* acc, int kh, int l) {
#pragma unroll
    for (int c = 0; c < 4; ++c) {
        bf16x8 bh = *(const bf16x8*)(Bhi + (kh * 4 + c) * 256 + l * 4);
        bf16x8 bl = *(const bf16x8*)(Blo + (kh * 4 + c) * 256 + l * 4);
        acc[c] = MFMA16(ahi, bh, acc[c], 0, 0, 0);
        acc[c] = MFMA16(ahi, bl, acc[c], 0, 0, 0);
        acc[c] = MFMA16(alo, bh, acc[c], 0, 0, 0);
    }
}

// ---------------- Kernel A: node MLP (persistent, readlane broadcasts) ----------------
__global__ __launch_bounds__(256) void node_mlp_kernel(
    const float* __restrict__ atom, const float* __restrict__ W1, const float* __restrict__ b1,
    const float* __restrict__ W2, const float* __restrict__ b2, float* __restrict__ mn)
{
    __shared__ float W1s[FDIM][FDIM];
    __shared__ float W2s[FDIM][FDIM];
    const int f = threadIdx.x, ty = threadIdx.y;
    const int tid = ty * 64 + f;
    for (int i = tid; i < FDIM * FDIM; i += 256) {
        ((float*)W1s)[i] = W1[i];
        ((float*)W2s)[i] = W2[i];
    }
    __syncthreads();
    const float bb1 = b1[f], bb2 = b2[f];
    const int nw = gridDim.x * 4;
    for (int n = blockIdx.x * 4 + ty; n < N_NODES; n += nw) {
        const float a = atom[n * FDIM + f];
        float h = bb1;
        for (int g = 0; g < FDIM; ++g) h += bcast_lane(a, g) * W1s[g][f];
        h = silu_f(h);
        float o = bb2;
        for (int g = 0; g < FDIM; ++g) o += bcast_lane(h, g) * W2s[g][f];
        mn[n * FDIM + f] = o;
    }
}

// ---------------- Kernel B: per-edge pipeline with MFMA matmuls ----------------
// Per wave-iter: 16 edges. Phase1 (lane=f): msg compute + fp32 atomAcc scatter + split/stage.
// MFMA phases: h1/h2 = silu(msg@Wq{1,2}a), e1/e2 = h@Wq{1,2}b via 16x16x32 bf16 3-term split.
// B-fragments of all 4 weight matrices pre-split into LDS once per block (64 KB).
__global__ __launch_bounds__(512) void edge_kernel(
    const float* __restrict__ dist,   // [E,20]
    const float* __restrict__ dir,    // [E,3]
    const int* __restrict__ eidx,     // [2,E] int32
    const float* __restrict__ mn,     // [N,F]
    const float* __restrict__ We,     // [20,F]
    const float* __restrict__ Wq1a, const float* __restrict__ Wq1b,
    const float* __restrict__ Wq2a, const float* __restrict__ Wq2b,
    const float* __restrict__ forceN, // [N,3,F]
    float* __restrict__ atomAcc,      // [N,F]
    float* __restrict__ forceAcc)     // [N,3,F]
{
    // B-frags: slot = ((mm*2+p)*2+kh)*4+c, each slot 64 lanes x 4 u32
    __shared__ __align__(16) unsigned Bfr[16384];        // 64 KB
    __shared__ __align__(16) unsigned Astg[8][16][76];   // per-wave staging, padded stride

    const int l = threadIdx.x;          // lane 0..63
    const int ty = threadIdx.y;         // wave 0..7
    const int q = l >> 4, row = l & 15;

    // ---- precompute B fragments (hi/lo split) ----
    for (int t = ty; t < 32; t += 8) {
        const int mm = t >> 3, kh = (t >> 2) & 1, c = t & 3;
        const float* W = (mm == 0) ? Wq1a : (mm == 1) ? Wq2a : (mm == 2) ? Wq1b : Wq2b;
        const int n = c * 16 + row;
        const int kb = kh * 32 + q * 8;
        unsigned* hiP = &Bfr[(((mm * 2 + 0) * 2 + kh) * 4 + c) * 256 + l * 4];
        unsigned* loP = &Bfr[(((mm * 2 + 1) * 2 + kh) * 4 + c) * 256 + l * 4];
#pragma unroll
        for (int i = 0; i < 4; ++i) {
            float w0 = W[(kb + 2 * i) * FDIM + n];
            float w1 = W[(kb + 2 * i + 1) * FDIM + n];
            unsigned h0 = bf16_rn(w0);
            unsigned l0 = bf16_rn(w0 - __uint_as_float(h0 << 16));
            unsigned h1 = bf16_rn(w1);
            unsigned l1 = bf16_rn(w1 - __uint_as_float(h1 << 16));
            hiP[i] = h0 | (h1 << 16);
            loP[i] = l0 | (l1 << 16);
        }
    }
    __syncthreads();

    const unsigned* B1aH = Bfr + 0 * 2048; const unsigned* B1aL = Bfr + 1 * 2048; // Wq1a
    const unsigned* B2aH = Bfr + 2 * 2048; const unsigned* B2aL = Bfr + 3 * 2048; // Wq2a
    const unsigned* B1bH = Bfr + 4 * 2048; const unsigned* B1bL = Bfr + 5 * 2048; // Wq1b
    const unsigned* B2bH = Bfr + 6 * 2048; const unsigned* B2bL = Bfr + 7 * 2048; // Wq2b

    float we[NB];
#pragma unroll
    for (int b = 0; b < NB; ++b) we[b] = We[b * FDIM + l];

    unsigned* stg = &Astg[ty][0][0];            // [16][76]
    const unsigned* rowPtr = &Astg[ty][row][0];

    const int ngroups = N_EDGES / 16;
    const int stride = gridDim.x * 8;
    for (int grp = blockIdx.x * 8 + ty; grp < ngroups; grp += stride) {
        const int e0 = grp * 16;

        // ---- phase 1: msg (lane = feature f = l), fp32 scatter, split+stage ----
#pragma unroll
        for (int j = 0; j < 16; ++j) {
            const int src = __builtin_amdgcn_readfirstlane(eidx[e0 + j]);
            const int dst = __builtin_amdgcn_readfirstlane(eidx[N_EDGES + e0 + j]);
            float me = 0.0f;
#pragma unroll
            for (int b = 0; b < NB; ++b) me += dist[(e0 + j) * NB + b] * we[b];
            const float m = me * mn[src * FDIM + l] * mn[dst * FDIM + l];
            atomicAdd(&atomAcc[src * FDIM + l], m);
            stg[j * 76 + l] = pack_split(m);
        }

        // ---- h-phase: h1 = msg@Wq1a, h2 = msg@Wq2a ----
        f32x4 acc1[4], acc2[4];
#pragma unroll
        for (int c = 0; c < 4; ++c) {
            acc1[c] = (f32x4){0.f, 0.f, 0.f, 0.f};
            acc2[c] = (f32x4){0.f, 0.f, 0.f, 0.f};
        }
#pragma unroll
        for (int kh = 0; kh < 2; ++kh) {
            bf16x8 ahi, alo;
            load_afrag(rowPtr, kh, q, &ahi, &alo);
            mm3(B1aH, B1aL, ahi, alo, acc1, kh, l);
            mm3(B2aH, B2aL, ahi, alo, acc2, kh, l);
        }
        // silu
#pragma unroll
        for (int c = 0; c < 4; ++c)
#pragma unroll
            for (int r = 0; r < 4; ++r) {
                acc1[c][r] = silu_f(acc1[c][r]);
                acc2[c][r] = silu_f(acc2[c][r]);
            }

        // ---- stage h1 (C layout: m = q*4+r, n = row+16c), then e1 = h1@Wq1b ----
#pragma unroll
        for (int c = 0; c < 4; ++c)
#pragma unroll
            for (int r = 0; r < 4; ++r)
                stg[(q * 4 + r) * 76 + (row + 16 * c)] = pack_split(acc1[c][r]);

        f32x4 eacc1[4];
#pragma unroll
        for (int c = 0; c < 4; ++c) eacc1[c] = (f32x4){0.f, 0.f, 0.f, 0.f};
#pragma unroll
        for (int kh = 0; kh < 2; ++kh) {
            bf16x8 ahi, alo;
            load_afrag(rowPtr, kh, q, &ahi, &alo);
            mm3(B1bH, B1bL, ahi, alo, eacc1, kh, l);
        }

        // ---- stage h2, then e2 = h2@Wq2b ----
#pragma unroll
        for (int c = 0; c < 4; ++c)
#pragma unroll
            for (int r = 0; r < 4; ++r)
                stg[(q * 4 + r) * 76 + (row + 16 * c)] = pack_split(acc2[c][r]);

        f32x4 eacc2[4];
#pragma unroll
        for (int c = 0; c < 4; ++c) eacc2[c] = (f32x4){0.f, 0.f, 0.f, 0.f};
#pragma unroll
        for (int kh = 0; kh < 2; ++kh) {
            bf16x8 ahi, alo;
            load_afrag(rowPtr, kh, q, &ahi, &alo);
            mm3(B2bH, B2bL, ahi, alo, eacc2, kh, l);
        }

        // ---- equivariant scatter: lane holds E[m=q*4+r][n=row+16c] ----
#pragma unroll
        for (int r = 0; r < 4; ++r) {
            const int em = e0 + q * 4 + r;
            const int vs = eidx[em];
            const int vd = eidx[N_EDGES + em];
            const float d0 = dir[em * 3 + 0];
            const float d1 = dir[em * 3 + 1];
            const float d2 = dir[em * 3 + 2];
            const float* fd = forceN + (size_t)vd * 3 * FDIM;
            float* fa = forceAcc + (size_t)vs * 3 * FDIM;
#pragma unroll
            for (int c = 0; c < 4; ++c) {
                const int n = row + 16 * c;
                const float a = eacc1[c][r];
                const float b = eacc2[c][r];
                atomicAdd(&fa[0 * FDIM + n], a * d0 + b * fd[0 * FDIM + n]);
                atomicAdd(&fa[1 * FDIM + n], a * d1 + b * fd[1 * FDIM + n]);
                atomicAdd(&fa[2 * FDIM + n], a * d2 + b * fd[2 * FDIM + n]);
            }
        }
    }
}

// ---------------- Kernel C: finalize nodes (inv_update2 + LayerNorm, persistent) ----------------
__global__ __launch_bounds__(256) void node_final_kernel(
    const float* __restrict__ Wu, const float* __restrict__ gamma, const float* __restrict__ beta,
    float* __restrict__ atomAcc,        // [N,F]
    const float* __restrict__ forceOut) // [N,3,F]
{
    __shared__ float Wus[FDIM][FDIM];
    const int f = threadIdx.x, ty = threadIdx.y;
    const int tid = ty * 64 + f;
    for (int i = tid; i < FDIM * FDIM; i += 256) ((float*)Wus)[i] = Wu[i];
    __syncthreads();
    const float gg = gamma[f], bb = beta[f];
    const int nw = gridDim.x * 4;
    for (int n = blockIdx.x * 4 + ty; n < N_NODES; n += nw) {
        const float f0 = forceOut[((size_t)n * 3 + 0) * FDIM + f];
        const float f1 = forceOut[((size_t)n * 3 + 1) * FDIM + f];
        const float f2 = forceOut[((size_t)n * 3 + 2) * FDIM + f];
        float r0 = 0.0f, r1 = 0.0f, r2 = 0.0f;
#pragma unroll 8
        for (int g = 0; g < FDIM; ++g) {
            const float w = Wus[g][f];
            r0 += bcast_lane(f0, g) * w;
            r1 += bcast_lane(f1, g) * w;
            r2 += bcast_lane(f2, g) * w;
        }
        float a = atomAcc[n * FDIM + f] + (f0 * r0 + f1 * r1 + f2 * r2);
        float s = a;
#pragma unroll
        for (int off = 32; off >= 1; off >>= 1) s += __shfl_xor(s, off, 64);
        const float mu = s * (1.0f / 64.0f);
        const float d = a - mu;
        float v = d * d;
#pragma unroll
        for (int off = 32; off >= 1; off >>= 1) v += __shfl_xor(v, off, 64);
        v *= (1.0f / 64.0f);
        atomAcc[n * FDIM + f] = d * rsqrtf(v + LN_EPS) * gg + bb;
    }
}

extern "C" void kernel_launch(void* const* d_in, const int* in_sizes, int n_in,
                              void* d_out, int out_size, void* d_ws, size_t ws_size,
                              hipStream_t stream)
{
    const float* atom_node  = (const float*)d_in[0];
    const float* force_node = (const float*)d_in[1];
    const float* dir_edge   = (const float*)d_in[2];
    const float* dist_edge  = (const float*)d_in[3];
    const int*   edge_index = (const int*)d_in[4];
    const float* W1   = (const float*)d_in[5];
    const float* b1   = (const float*)d_in[6];
    const float* W2   = (const float*)d_in[7];
    const float* b2   = (const float*)d_in[8];
    const float* We   = (const float*)d_in[9];
    const float* Wq1a = (const float*)d_in[10];
    const float* Wq1b = (const float*)d_in[11];
    const float* Wq2a = (const float*)d_in[12];
    const float* Wq2b = (const float*)d_in[13];
    const float* Wu   = (const float*)d_in[14];
    const float* gamma = (const float*)d_in[15];
    const float* beta  = (const float*)d_in[16];

    float* atomOut  = (float*)d_out;                          // [N,F]
    float* forceOut = (float*)d_out + (size_t)N_NODES * FDIM; // [N,3,F]
    float* mn = (float*)d_ws;                                 // [N,F] scratch

    hipMemcpyAsync(atomOut, atom_node, (size_t)N_NODES * FDIM * sizeof(float),
                   hipMemcpyDeviceToDevice, stream);
    hipMemcpyAsync(forceOut, force_node, (size_t)N_NODES * 3 * FDIM * sizeof(float),
                   hipMemcpyDeviceToDevice, stream);

    dim3 blk4(64, 4);
    dim3 blk8(64, 8);
    node_mlp_kernel<<<512, blk4, 0, stream>>>(atom_node, W1, b1, W2, b2, mn);
    edge_kernel<<<256, blk8, 0, stream>>>(dist_edge, dir_edge, edge_index, mn, We,
                                          Wq1a, Wq1b, Wq2a, Wq2b, force_node,
                                          atomOut, forceOut);
    node_final_kernel<<<512, blk4, 0, stream>>>(Wu, gamma, beta, atomOut, forceOut);
}

// Round 6
// 634.724 us; speedup vs baseline: 2.2257x; 1.0587x over previous
//
#include <hip/hip_runtime.h>

#define N_NODES 20000
#define N_EDGES 640000
#define FDIM 64
#define NB 20
#define LN_EPS 1e-5f

typedef __attribute__((ext_vector_type(8))) short bf16x8;
typedef __attribute__((ext_vector_type(4))) float f32x4;

#define SEL_HI 0x07060302u   // {hi16(s0), hi16(s1)} -> bf16 pair (even k in low half)
#define SEL_LO 0x05040100u   // {lo16(s0), lo16(s1)}
#define MFMA16 __builtin_amdgcn_mfma_f32_16x16x32_bf16

__device__ __forceinline__ float silu_f(float x) { return x / (1.0f + __expf(-x)); }

__device__ __forceinline__ float bcast_lane(float v, int lane) {
    return __int_as_float(__builtin_amdgcn_readlane(__float_as_int(v), lane));
}

__device__ __forceinline__ unsigned bf16_rn(float x) {
    unsigned u = __float_as_uint(x);
    return (u + 0x7FFFu + ((u >> 16) & 1u)) >> 16;
}

// split x into bf16 hi/lo planes, packed (hi<<16)|lo
__device__ __forceinline__ unsigned pack_split(float x) {
    unsigned h = bf16_rn(x);
    unsigned lo = bf16_rn(x - __uint_as_float(h << 16));
    return (h << 16) | lo;
}

// Build A-fragments (hi & lo planes) for one K-half from a staged row of packed u32s.
__device__ __forceinline__ void load_afrag(const unsigned* rowPtr, int kh, int q,
                                           bf16x8* ahi, bf16x8* alo) {
    const uint4 ra = *(const uint4*)(rowPtr + kh * 32 + q * 8);
    const uint4 rb = *(const uint4*)(rowPtr + kh * 32 + q * 8 + 4);
    union { unsigned u[4]; bf16x8 v; } H, L;
    H.u[0] = __builtin_amdgcn_perm(ra.y, ra.x, SEL_HI);
    H.u[1] = __builtin_amdgcn_perm(ra.w, ra.z, SEL_HI);
    H.u[2] = __builtin_amdgcn_perm(rb.y, rb.x, SEL_HI);
    H.u[3] = __builtin_amdgcn_perm(rb.w, rb.z, SEL_HI);
    L.u[0] = __builtin_amdgcn_perm(ra.y, ra.x, SEL_LO);
    L.u[1] = __builtin_amdgcn_perm(ra.w, ra.z, SEL_LO);
    L.u[2] = __builtin_amdgcn_perm(rb.y, rb.x, SEL_LO);
    L.u[3] = __builtin_amdgcn_perm(rb.w, rb.z, SEL_LO);
    *ahi = H.v;
    *alo = L.v;
}

// 3-term fp32-via-bf16 accumulation for one K-half over all 4 N-chunks.
__device__ __forceinline__ void mm3(const unsigned* Bhi, const unsigned* Blo,
                                    bf16x8 ahi, bf16x8 alo, f32x4* acc, int kh, int l) {
#pragma unroll
    for (int c = 0; c < 4; ++c) {
        bf16x8 bh = *(const bf16x8*)(Bhi + (kh * 4 + c) * 256 + l * 4);
        bf16x8 bl = *(const bf16x8*)(Blo + (kh * 4 + c) * 256 + l * 4);
        acc[c] = MFMA16(ahi, bh, acc[c], 0, 0, 0);
        acc[c] = MFMA16(ahi, bl, acc[c], 0, 0, 0);
        acc[c] = MFMA16(alo, bh, acc[c], 0, 0, 0);
    }
}

// ---------------- Kernel A: node MLP (persistent, readlane broadcasts) ----------------
__global__ __launch_bounds__(256) void node_mlp_kernel(
    const float* __restrict__ atom, const float* __restrict__ W1, const float* __restrict__ b1,
    const float* __restrict__ W2, const float* __restrict__ b2, float* __restrict__ mn)
{
    __shared__ float W1s[FDIM][FDIM];
    __shared__ float W2s[FDIM][FDIM];
    const int f = threadIdx.x, ty = threadIdx.y;
    const int tid = ty * 64 + f;
    for (int i = tid; i < FDIM * FDIM; i += 256) {
        ((float*)W1s)[i] = W1[i];
        ((float*)W2s)[i] = W2[i];
    }
    __syncthreads();
    const float bb1 = b1[f], bb2 = b2[f];
    const int nw = gridDim.x * 4;
    for (int n = blockIdx.x * 4 + ty; n < N_NODES; n += nw) {
        const float a = atom[n * FDIM + f];
        float h = bb1;
        for (int g = 0; g < FDIM; ++g) h += bcast_lane(a, g) * W1s[g][f];
        h = silu_f(h);
        float o = bb2;
        for (int g = 0; g < FDIM; ++g) o += bcast_lane(h, g) * W2s[g][f];
        mn[n * FDIM + f] = o;
    }
}

// ---------------- Kernel B: per-edge MFMA pipeline, 16 waves/block for occupancy ----------------
// One 1024-thread block per CU: B-fragments (64 KB) shared by 16 waves; per-wave staging
// 16x76 u32 (padded stride kills bank conflicts). LDS total ~140 KB -> 16 waves/CU (50%).
__global__ __launch_bounds__(1024) void edge_kernel(
    const float* __restrict__ dist,   // [E,20]
    const float* __restrict__ dir,    // [E,3]
    const int* __restrict__ eidx,     // [2,E] int32
    const float* __restrict__ mn,     // [N,F]
    const float* __restrict__ We,     // [20,F]
    const float* __restrict__ Wq1a, const float* __restrict__ Wq1b,
    const float* __restrict__ Wq2a, const float* __restrict__ Wq2b,
    const float* __restrict__ forceN, // [N,3,F]
    float* __restrict__ atomAcc,      // [N,F]
    float* __restrict__ forceAcc)     // [N,3,F]
{
    // B-frags: slot = ((mm*2+p)*2+kh)*4+c, each slot 64 lanes x 4 u32
    __shared__ __align__(16) unsigned Bfr[16384];         // 64 KB
    __shared__ __align__(16) unsigned Astg[16][16][76];   // per-wave staging, padded stride

    const int l = threadIdx.x;          // lane 0..63
    const int ty = threadIdx.y;         // wave 0..15
    const int q = l >> 4, row = l & 15;

    // ---- precompute B fragments (hi/lo split) ----
    for (int t = ty; t < 32; t += 16) {
        const int mm = t >> 3, kh = (t >> 2) & 1, c = t & 3;
        const float* W = (mm == 0) ? Wq1a : (mm == 1) ? Wq2a : (mm == 2) ? Wq1b : Wq2b;
        const int n = c * 16 + row;
        const int kb = kh * 32 + q * 8;
        unsigned* hiP = &Bfr[(((mm * 2 + 0) * 2 + kh) * 4 + c) * 256 + l * 4];
        unsigned* loP = &Bfr[(((mm * 2 + 1) * 2 + kh) * 4 + c) * 256 + l * 4];
#pragma unroll
        for (int i = 0; i < 4; ++i) {
            float w0 = W[(kb + 2 * i) * FDIM + n];
            float w1 = W[(kb + 2 * i + 1) * FDIM + n];
            unsigned h0 = bf16_rn(w0);
            unsigned l0 = bf16_rn(w0 - __uint_as_float(h0 << 16));
            unsigned h1 = bf16_rn(w1);
            unsigned l1 = bf16_rn(w1 - __uint_as_float(h1 << 16));
            hiP[i] = h0 | (h1 << 16);
            loP[i] = l0 | (l1 << 16);
        }
    }
    __syncthreads();

    const unsigned* B1aH = Bfr + 0 * 2048; const unsigned* B1aL = Bfr + 1 * 2048; // Wq1a
    const unsigned* B2aH = Bfr + 2 * 2048; const unsigned* B2aL = Bfr + 3 * 2048; // Wq2a
    const unsigned* B1bH = Bfr + 4 * 2048; const unsigned* B1bL = Bfr + 5 * 2048; // Wq1b
    const unsigned* B2bH = Bfr + 6 * 2048; const unsigned* B2bL = Bfr + 7 * 2048; // Wq2b

    float we[NB];
#pragma unroll
    for (int b = 0; b < NB; ++b) we[b] = We[b * FDIM + l];

    unsigned* stg = &Astg[ty][0][0];            // [16][76]
    const unsigned* rowPtr = &Astg[ty][row][0];

    const int ngroups = N_EDGES / 16;
    const int stride = gridDim.x * 16;
    for (int grp = blockIdx.x * 16 + ty; grp < ngroups; grp += stride) {
        const int e0 = grp * 16;

        // ---- phase 1: msg (lane = feature f = l), fp32 scatter, split+stage ----
#pragma unroll
        for (int j = 0; j < 16; ++j) {
            const int src = __builtin_amdgcn_readfirstlane(eidx[e0 + j]);
            const int dst = __builtin_amdgcn_readfirstlane(eidx[N_EDGES + e0 + j]);
            float me = 0.0f;
#pragma unroll
            for (int b = 0; b < NB; ++b) me += dist[(e0 + j) * NB + b] * we[b];
            const float m = me * mn[src * FDIM + l] * mn[dst * FDIM + l];
            atomicAdd(&atomAcc[src * FDIM + l], m);
            stg[j * 76 + l] = pack_split(m);
        }

        // ---- h-phase: h1 = msg@Wq1a, h2 = msg@Wq2a ----
        f32x4 acc1[4], acc2[4];
#pragma unroll
        for (int c = 0; c < 4; ++c) {
            acc1[c] = (f32x4){0.f, 0.f, 0.f, 0.f};
            acc2[c] = (f32x4){0.f, 0.f, 0.f, 0.f};
        }
#pragma unroll
        for (int kh = 0; kh < 2; ++kh) {
            bf16x8 ahi, alo;
            load_afrag(rowPtr, kh, q, &ahi, &alo);
            mm3(B1aH, B1aL, ahi, alo, acc1, kh, l);
            mm3(B2aH, B2aL, ahi, alo, acc2, kh, l);
        }
        // silu
#pragma unroll
        for (int c = 0; c < 4; ++c)
#pragma unroll
            for (int r = 0; r < 4; ++r) {
                acc1[c][r] = silu_f(acc1[c][r]);
                acc2[c][r] = silu_f(acc2[c][r]);
            }

        // ---- stage h1 (C layout: m = q*4+r, n = row+16c), then e1 = h1@Wq1b ----
#pragma unroll
        for (int c = 0; c < 4; ++c)
#pragma unroll
            for (int r = 0; r < 4; ++r)
                stg[(q * 4 + r) * 76 + (row + 16 * c)] = pack_split(acc1[c][r]);

        f32x4 eacc1[4];
#pragma unroll
        for (int c = 0; c < 4; ++c) eacc1[c] = (f32x4){0.f, 0.f, 0.f, 0.f};
#pragma unroll
        for (int kh = 0; kh < 2; ++kh) {
            bf16x8 ahi, alo;
            load_afrag(rowPtr, kh, q, &ahi, &alo);
            mm3(B1bH, B1bL, ahi, alo, eacc1, kh, l);
        }

        // ---- stage h2, then e2 = h2@Wq2b ----
#pragma unroll
        for (int c = 0; c < 4; ++c)
#pragma unroll
            for (int r = 0; r < 4; ++r)
                stg[(q * 4 + r) * 76 + (row + 16 * c)] = pack_split(acc2[c][r]);

        f32x4 eacc2[4];
#pragma unroll
        for (int c = 0; c < 4; ++c) eacc2[c] = (f32x4){0.f, 0.f, 0.f, 0.f};
#pragma unroll
        for (int kh = 0; kh < 2; ++kh) {
            bf16x8 ahi, alo;
            load_afrag(rowPtr, kh, q, &ahi, &alo);
            mm3(B2bH, B2bL, ahi, alo, eacc2, kh, l);
        }

        // ---- equivariant scatter: lane holds E[m=q*4+r][n=row+16c] ----
#pragma unroll
        for (int r = 0; r < 4; ++r) {
            const int em = e0 + q * 4 + r;
            const int vs = eidx[em];
            const int vd = eidx[N_EDGES + em];
            const float d0 = dir[em * 3 + 0];
            const float d1 = dir[em * 3 + 1];
            const float d2 = dir[em * 3 + 2];
            const float* fd = forceN + (size_t)vd * 3 * FDIM;
            float* fa = forceAcc + (size_t)vs * 3 * FDIM;
#pragma unroll
            for (int c = 0; c < 4; ++c) {
                const int n = row + 16 * c;
                const float a = eacc1[c][r];
                const float b = eacc2[c][r];
                atomicAdd(&fa[0 * FDIM + n], a * d0 + b * fd[0 * FDIM + n]);
                atomicAdd(&fa[1 * FDIM + n], a * d1 + b * fd[1 * FDIM + n]);
                atomicAdd(&fa[2 * FDIM + n], a * d2 + b * fd[2 * FDIM + n]);
            }
        }
    }
}

// ---------------- Kernel C: finalize nodes (inv_update2 + LayerNorm, persistent) ----------------
__global__ __launch_bounds__(256) void node_final_kernel(
    const float* __restrict__ Wu, const float* __restrict__ gamma, const float* __restrict__ beta,
    float* __restrict__ atomAcc,        // [N,F]
    const float* __restrict__ forceOut) // [N,3,F]
{
    __shared__ float Wus[FDIM][FDIM];
    const int f = threadIdx.x, ty = threadIdx.y;
    const int tid = ty * 64 + f;
    for (int i = tid; i < FDIM * FDIM; i += 256) ((float*)Wus)[i] = Wu[i];
    __syncthreads();
    const float gg = gamma[f], bb = beta[f];
    const int nw = gridDim.x * 4;
    for (int n = blockIdx.x * 4 + ty; n < N_NODES; n += nw) {
        const float f0 = forceOut[((size_t)n * 3 + 0) * FDIM + f];
        const float f1 = forceOut[((size_t)n * 3 + 1) * FDIM + f];
        const float f2 = forceOut[((size_t)n * 3 + 2) * FDIM + f];
        float r0 = 0.0f, r1 = 0.0f, r2 = 0.0f;
#pragma unroll 8
        for (int g = 0; g < FDIM; ++g) {
            const float w = Wus[g][f];
            r0 += bcast_lane(f0, g) * w;
            r1 += bcast_lane(f1, g) * w;
            r2 += bcast_lane(f2, g) * w;
        }
        float a = atomAcc[n * FDIM + f] + (f0 * r0 + f1 * r1 + f2 * r2);
        float s = a;
#pragma unroll
        for (int off = 32; off >= 1; off >>= 1) s += __shfl_xor(s, off, 64);
        const float mu = s * (1.0f / 64.0f);
        const float d = a - mu;
        float v = d * d;
#pragma unroll
        for (int off = 32; off >= 1; off >>= 1) v += __shfl_xor(v, off, 64);
        v *= (1.0f / 64.0f);
        atomAcc[n * FDIM + f] = d * rsqrtf(v + LN_EPS) * gg + bb;
    }
}

extern "C" void kernel_launch(void* const* d_in, const int* in_sizes, int n_in,
                              void* d_out, int out_size, void* d_ws, size_t ws_size,
                              hipStream_t stream)
{
    const float* atom_node  = (const float*)d_in[0];
    const float* force_node = (const float*)d_in[1];
    const float* dir_edge   = (const float*)d_in[2];
    const float* dist_edge  = (const float*)d_in[3];
    const int*   edge_index = (const int*)d_in[4];
    const float* W1   = (const float*)d_in[5];
    const float* b1   = (const float*)d_in[6];
    const float* W2   = (const float*)d_in[7];
    const float* b2   = (const float*)d_in[8];
    const float* We   = (const float*)d_in[9];
    const float* Wq1a = (const float*)d_in[10];
    const float* Wq1b = (const float*)d_in[11];
    const float* Wq2a = (const float*)d_in[12];
    const float* Wq2b = (const float*)d_in[13];
    const float* Wu   = (const float*)d_in[14];
    const float* gamma = (const float*)d_in[15];
    const float* beta  = (const float*)d_in[16];

    float* atomOut  = (float*)d_out;                          // [N,F]
    float* forceOut = (float*)d_out + (size_t)N_NODES * FDIM; // [N,3,F]
    float* mn = (float*)d_ws;                                 // [N,F] scratch

    hipMemcpyAsync(atomOut, atom_node, (size_t)N_NODES * FDIM * sizeof(float),
                   hipMemcpyDeviceToDevice, stream);
    hipMemcpyAsync(forceOut, force_node, (size_t)N_NODES * 3 * FDIM * sizeof(float),
                   hipMemcpyDeviceToDevice, stream);

    dim3 blk4(64, 4);
    dim3 blk16(64, 16);
    node_mlp_kernel<<<512, blk4, 0, stream>>>(atom_node, W1, b1, W2, b2, mn);
    edge_kernel<<<256, blk16, 0, stream>>>(dist_edge, dir_edge, edge_index, mn, We,
                                           Wq1a, Wq1b, Wq2a, Wq2b, force_node,
                                           atomOut, forceOut);
    node_final_kernel<<<512, blk4, 0, stream>>>(Wu, gamma, beta, atomOut, forceOut);
}

// Round 7
// 606.844 us; speedup vs baseline: 2.3279x; 1.0459x over previous
//
#include <hip/hip_runtime.h>

#define N_NODES 20000
#define N_EDGES 640000
#define FDIM 64
#define NB 20
#define LN_EPS 1e-5f

typedef __attribute__((ext_vector_type(8))) short bf16x8;
typedef __attribute__((ext_vector_type(4))) float f32x4;

#define SEL_HI 0x07060302u   // {hi16(s0), hi16(s1)} -> bf16 pair (even k in low half)
#define SEL_LO 0x05040100u   // {lo16(s0), lo16(s1)}
#define MFMA16 __builtin_amdgcn_mfma_f32_16x16x32_bf16

__device__ __forceinline__ float silu_f(float x) { return x / (1.0f + __expf(-x)); }

__device__ __forceinline__ float bcast_lane(float v, int lane) {
    return __int_as_float(__builtin_amdgcn_readlane(__float_as_int(v), lane));
}

__device__ __forceinline__ unsigned bf16_rn(float x) {
    unsigned u = __float_as_uint(x);
    return (u + 0x7FFFu + ((u >> 16) & 1u)) >> 16;
}

// split x into bf16 hi/lo planes, packed (hi<<16)|lo
__device__ __forceinline__ unsigned pack_split(float x) {
    unsigned h = bf16_rn(x);
    unsigned lo = bf16_rn(x - __uint_as_float(h << 16));
    return (h << 16) | lo;
}

// Build A-fragments (hi & lo planes) for one K-half from a staged row of packed u32s.
__device__ __forceinline__ void load_afrag(const unsigned* rowPtr, int kh, int q,
                                           bf16x8* ahi, bf16x8* alo) {
    const uint4 ra = *(const uint4*)(rowPtr + kh * 32 + q * 8);
    const uint4 rb = *(const uint4*)(rowPtr + kh * 32 + q * 8 + 4);
    union { unsigned u[4]; bf16x8 v; } H, L;
    H.u[0] = __builtin_amdgcn_perm(ra.y, ra.x, SEL_HI);
    H.u[1] = __builtin_amdgcn_perm(ra.w, ra.z, SEL_HI);
    H.u[2] = __builtin_amdgcn_perm(rb.y, rb.x, SEL_HI);
    H.u[3] = __builtin_amdgcn_perm(rb.w, rb.z, SEL_HI);
    L.u[0] = __builtin_amdgcn_perm(ra.y, ra.x, SEL_LO);
    L.u[1] = __builtin_amdgcn_perm(ra.w, ra.z, SEL_LO);
    L.u[2] = __builtin_amdgcn_perm(rb.y, rb.x, SEL_LO);
    L.u[3] = __builtin_amdgcn_perm(rb.w, rb.z, SEL_LO);
    *ahi = H.v;
    *alo = L.v;
}

// 3-term fp32-via-bf16 accumulation for one K-half over all 4 N-chunks.
__device__ __forceinline__ void mm3(const unsigned* Bhi, const unsigned* Blo,
                                    bf16x8 ahi, bf16x8 alo, f32x4* acc, int kh, int l) {
#pragma unroll
    for (int c = 0; c < 4; ++c) {
        bf16x8 bh = *(const bf16x8*)(Bhi + (kh * 4 + c) * 256 + l * 4);
        bf16x8 bl = *(const bf16x8*)(Blo + (kh * 4 + c) * 256 + l * 4);
        acc[c] = MFMA16(ahi, bh, acc[c], 0, 0, 0);
        acc[c] = MFMA16(ahi, bl, acc[c], 0, 0, 0);
        acc[c] = MFMA16(alo, bh, acc[c], 0, 0, 0);
    }
}

// ---------------- Kernel A: node MLP (persistent, readlane broadcasts) ----------------
__global__ __launch_bounds__(256) void node_mlp_kernel(
    const float* __restrict__ atom, const float* __restrict__ W1, const float* __restrict__ b1,
    const float* __restrict__ W2, const float* __restrict__ b2, float* __restrict__ mn)
{
    __shared__ float W1s[FDIM][FDIM];
    __shared__ float W2s[FDIM][FDIM];
    const int f = threadIdx.x, ty = threadIdx.y;
    const int tid = ty * 64 + f;
    for (int i = tid; i < FDIM * FDIM; i += 256) {
        ((float*)W1s)[i] = W1[i];
        ((float*)W2s)[i] = W2[i];
    }
    __syncthreads();
    const float bb1 = b1[f], bb2 = b2[f];
    const int nw = gridDim.x * 4;
    for (int n = blockIdx.x * 4 + ty; n < N_NODES; n += nw) {
        const float a = atom[n * FDIM + f];
        float h = bb1;
        for (int g = 0; g < FDIM; ++g) h += bcast_lane(a, g) * W1s[g][f];
        h = silu_f(h);
        float o = bb2;
        for (int g = 0; g < FDIM; ++g) o += bcast_lane(h, g) * W2s[g][f];
        mn[n * FDIM + f] = o;
    }
}

// ---------------- Kernel B: per-edge MFMA pipeline ----------------
// 16 waves/block (one block/CU). me = dist@We done with MFMA from coalesced float4 loads
// (kills 320 broadcast VMEM loads + 320 FMAs per group). eidx/dir vectorized + readlane/shfl.
__global__ __launch_bounds__(1024) void edge_kernel(
    const float* __restrict__ dist,   // [E,20]
    const float* __restrict__ dir,    // [E,3]
    const int* __restrict__ eidx,     // [2,E] int32
    const float* __restrict__ mn,     // [N,F]
    const float* __restrict__ We,     // [20,F]
    const float* __restrict__ Wq1a, const float* __restrict__ Wq1b,
    const float* __restrict__ Wq2a, const float* __restrict__ Wq2b,
    const float* __restrict__ forceN, // [N,3,F]
    float* __restrict__ atomAcc,      // [N,F]
    float* __restrict__ forceAcc)     // [N,3,F]
{
    __shared__ __align__(16) unsigned Bfr[16384];         // 64 KB: Wq1a/Wq2a/Wq1b/Wq2b frags
    __shared__ __align__(16) unsigned WeFr[2048];         // 8 KB: We frags (K padded to 32)
    __shared__ __align__(16) unsigned Astg[16][16][76];   // per-wave staging, padded stride

    const int l = threadIdx.x;          // lane 0..63
    const int ty = threadIdx.y;         // wave 0..15
    const int q = l >> 4, row = l & 15;

    // ---- precompute B fragments (hi/lo split) for the four 64x64 weights ----
    for (int t = ty; t < 32; t += 16) {
        const int mm = t >> 3, kh = (t >> 2) & 1, c = t & 3;
        const float* W = (mm == 0) ? Wq1a : (mm == 1) ? Wq2a : (mm == 2) ? Wq1b : Wq2b;
        const int n = c * 16 + row;
        const int kb = kh * 32 + q * 8;
        unsigned* hiP = &Bfr[(((mm * 2 + 0) * 2 + kh) * 4 + c) * 256 + l * 4];
        unsigned* loP = &Bfr[(((mm * 2 + 1) * 2 + kh) * 4 + c) * 256 + l * 4];
#pragma unroll
        for (int i = 0; i < 4; ++i) {
            float w0 = W[(kb + 2 * i) * FDIM + n];
            float w1 = W[(kb + 2 * i + 1) * FDIM + n];
            unsigned h0 = bf16_rn(w0);
            unsigned l0 = bf16_rn(w0 - __uint_as_float(h0 << 16));
            unsigned h1 = bf16_rn(w1);
            unsigned l1 = bf16_rn(w1 - __uint_as_float(h1 << 16));
            hiP[i] = h0 | (h1 << 16);
            loP[i] = l0 | (l1 << 16);
        }
    }
    // ---- precompute We fragments (20 x 64, K zero-padded to 32) ----
    for (int c = ty; c < 4; c += 16) {
        const int n = c * 16 + row;
        unsigned* hiP = &WeFr[(0 * 4 + c) * 256 + l * 4];
        unsigned* loP = &WeFr[(1 * 4 + c) * 256 + l * 4];
#pragma unroll
        for (int i = 0; i < 4; ++i) {
            const int k0 = q * 8 + 2 * i, k1 = k0 + 1;
            float w0 = (k0 < NB) ? We[k0 * FDIM + n] : 0.0f;
            float w1 = (k1 < NB) ? We[k1 * FDIM + n] : 0.0f;
            unsigned h0 = bf16_rn(w0);
            unsigned l0 = bf16_rn(w0 - __uint_as_float(h0 << 16));
            unsigned h1 = bf16_rn(w1);
            unsigned l1 = bf16_rn(w1 - __uint_as_float(h1 << 16));
            hiP[i] = h0 | (h1 << 16);
            loP[i] = l0 | (l1 << 16);
        }
    }
    __syncthreads();

    const unsigned* B1aH = Bfr + 0 * 2048; const unsigned* B1aL = Bfr + 1 * 2048; // Wq1a
    const unsigned* B2aH = Bfr + 2 * 2048; const unsigned* B2aL = Bfr + 3 * 2048; // Wq2a
    const unsigned* B1bH = Bfr + 4 * 2048; const unsigned* B1bL = Bfr + 5 * 2048; // Wq1b
    const unsigned* B2bH = Bfr + 6 * 2048; const unsigned* B2bL = Bfr + 7 * 2048; // Wq2b
    const unsigned* WeH = WeFr;            const unsigned* WeL = WeFr + 1024;

    unsigned* stg = &Astg[ty][0][0];            // [16][76]
    const unsigned* rowPtr = &Astg[ty][row][0];

    const int ngroups = N_EDGES / 16;
    const int stride = gridDim.x * 16;
    for (int grp = blockIdx.x * 16 + ty; grp < ngroups; grp += stride) {
        const int e0 = grp * 16;

        // ---- vectorized edge metadata: lanes 0..15 src, 16..31 dst; lanes 0..47 dir ----
        int ev = 0;
        if (l < 32) ev = eidx[(l < 16) ? (e0 + l) : (N_EDGES + e0 + (l - 16))];
        float dv = (l < 48) ? dir[e0 * 3 + l] : 0.0f;

        // ---- me = dist16x20 @ We20x64 via MFMA (K padded to 32) ----
        const float* dp = dist + (size_t)(e0 + row) * NB + q * 8;
        float4 da = {0.f, 0.f, 0.f, 0.f}, db = {0.f, 0.f, 0.f, 0.f};
        if (q < 2)       { da = *(const float4*)dp; db = *(const float4*)(dp + 4); }
        else if (q == 2) { da = *(const float4*)dp; }          // k = 16..19, rest zero
        unsigned s0 = pack_split(da.x), s1 = pack_split(da.y);
        unsigned s2 = pack_split(da.z), s3 = pack_split(da.w);
        unsigned s4 = pack_split(db.x), s5 = pack_split(db.y);
        unsigned s6 = pack_split(db.z), s7 = pack_split(db.w);
        union { unsigned u[4]; bf16x8 v; } AH, AL;
        AH.u[0] = __builtin_amdgcn_perm(s1, s0, SEL_HI);
        AH.u[1] = __builtin_amdgcn_perm(s3, s2, SEL_HI);
        AH.u[2] = __builtin_amdgcn_perm(s5, s4, SEL_HI);
        AH.u[3] = __builtin_amdgcn_perm(s7, s6, SEL_HI);
        AL.u[0] = __builtin_amdgcn_perm(s1, s0, SEL_LO);
        AL.u[1] = __builtin_amdgcn_perm(s3, s2, SEL_LO);
        AL.u[2] = __builtin_amdgcn_perm(s5, s4, SEL_LO);
        AL.u[3] = __builtin_amdgcn_perm(s7, s6, SEL_LO);

        f32x4 me4[4];
#pragma unroll
        for (int c = 0; c < 4; ++c) me4[c] = (f32x4){0.f, 0.f, 0.f, 0.f};
        mm3(WeH, WeL, AH.v, AL.v, me4, 0, l);

        // transpose me (C layout: m=q*4+r, n=row+16c) to stg[m][n] as raw f32
#pragma unroll
        for (int c = 0; c < 4; ++c)
#pragma unroll
            for (int r = 0; r < 4; ++r)
                stg[(q * 4 + r) * 76 + (row + 16 * c)] = __float_as_uint(me4[c][r]);

        // ---- per-edge: msg = me * mn[src] * mn[dst]; fp32 scatter; repack to stg ----
#pragma unroll
        for (int j = 0; j < 16; ++j) {
            const int src = __builtin_amdgcn_readlane(ev, j);
            const int dst = __builtin_amdgcn_readlane(ev, 16 + j);
            const float me = __uint_as_float(stg[j * 76 + l]);
            const float m = me * mn[src * FDIM + l] * mn[dst * FDIM + l];
            atomicAdd(&atomAcc[src * FDIM + l], m);
            stg[j * 76 + l] = pack_split(m);
        }

        // ---- h-phase: h1 = msg@Wq1a, h2 = msg@Wq2a ----
        f32x4 acc1[4], acc2[4];
#pragma unroll
        for (int c = 0; c < 4; ++c) {
            acc1[c] = (f32x4){0.f, 0.f, 0.f, 0.f};
            acc2[c] = (f32x4){0.f, 0.f, 0.f, 0.f};
        }
#pragma unroll
        for (int kh = 0; kh < 2; ++kh) {
            bf16x8 ahi, alo;
            load_afrag(rowPtr, kh, q, &ahi, &alo);
            mm3(B1aH, B1aL, ahi, alo, acc1, kh, l);
            mm3(B2aH, B2aL, ahi, alo, acc2, kh, l);
        }
#pragma unroll
        for (int c = 0; c < 4; ++c)
#pragma unroll
            for (int r = 0; r < 4; ++r) {
                acc1[c][r] = silu_f(acc1[c][r]);
                acc2[c][r] = silu_f(acc2[c][r]);
            }

        // ---- stage h1, e1 = h1@Wq1b ----
#pragma unroll
        for (int c = 0; c < 4; ++c)
#pragma unroll
            for (int r = 0; r < 4; ++r)
                stg[(q * 4 + r) * 76 + (row + 16 * c)] = pack_split(acc1[c][r]);

        f32x4 eacc1[4];
#pragma unroll
        for (int c = 0; c < 4; ++c) eacc1[c] = (f32x4){0.f, 0.f, 0.f, 0.f};
#pragma unroll
        for (int kh = 0; kh < 2; ++kh) {
            bf16x8 ahi, alo;
            load_afrag(rowPtr, kh, q, &ahi, &alo);
            mm3(B1bH, B1bL, ahi, alo, eacc1, kh, l);
        }

        // ---- stage h2, e2 = h2@Wq2b ----
#pragma unroll
        for (int c = 0; c < 4; ++c)
#pragma unroll
            for (int r = 0; r < 4; ++r)
                stg[(q * 4 + r) * 76 + (row + 16 * c)] = pack_split(acc2[c][r]);

        f32x4 eacc2[4];
#pragma unroll
        for (int c = 0; c < 4; ++c) eacc2[c] = (f32x4){0.f, 0.f, 0.f, 0.f};
#pragma unroll
        for (int kh = 0; kh < 2; ++kh) {
            bf16x8 ahi, alo;
            load_afrag(rowPtr, kh, q, &ahi, &alo);
            mm3(B2bH, B2bL, ahi, alo, eacc2, kh, l);
        }

        // ---- equivariant scatter: lane holds E[m=q*4+r][n=row+16c] ----
#pragma unroll
        for (int r = 0; r < 4; ++r) {
            const int eo = q * 4 + r;                 // lane-varying edge-in-group
            const int vs = __shfl(ev, eo);
            const int vd = __shfl(ev, 16 + eo);
            const float d0 = __shfl(dv, eo * 3 + 0);
            const float d1 = __shfl(dv, eo * 3 + 1);
            const float d2 = __shfl(dv, eo * 3 + 2);
            const float* fd = forceN + (size_t)vd * 3 * FDIM;
            float* fa = forceAcc + (size_t)vs * 3 * FDIM;
#pragma unroll
            for (int c = 0; c < 4; ++c) {
                const int n = row + 16 * c;
                const float a = eacc1[c][r];
                const float b = eacc2[c][r];
                atomicAdd(&fa[0 * FDIM + n], a * d0 + b * fd[0 * FDIM + n]);
                atomicAdd(&fa[1 * FDIM + n], a * d1 + b * fd[1 * FDIM + n]);
                atomicAdd(&fa[2 * FDIM + n], a * d2 + b * fd[2 * FDIM + n]);
            }
        }
    }
}

// ---------------- Kernel C: finalize nodes (inv_update2 + LayerNorm, persistent) ----------------
__global__ __launch_bounds__(256) void node_final_kernel(
    const float* __restrict__ Wu, const float* __restrict__ gamma, const float* __restrict__ beta,
    float* __restrict__ atomAcc,        // [N,F]
    const float* __restrict__ forceOut) // [N,3,F]
{
    __shared__ float Wus[FDIM][FDIM];
    const int f = threadIdx.x, ty = threadIdx.y;
    const int tid = ty * 64 + f;
    for (int i = tid; i < FDIM * FDIM; i += 256) ((float*)Wus)[i] = Wu[i];
    __syncthreads();
    const float gg = gamma[f], bb = beta[f];
    const int nw = gridDim.x * 4;
    for (int n = blockIdx.x * 4 + ty; n < N_NODES; n += nw) {
        const float f0 = forceOut[((size_t)n * 3 + 0) * FDIM + f];
        const float f1 = forceOut[((size_t)n * 3 + 1) * FDIM + f];
        const float f2 = forceOut[((size_t)n * 3 + 2) * FDIM + f];
        float r0 = 0.0f, r1 = 0.0f, r2 = 0.0f;
#pragma unroll 8
        for (int g = 0; g < FDIM; ++g) {
            const float w = Wus[g][f];
            r0 += bcast_lane(f0, g) * w;
            r1 += bcast_lane(f1, g) * w;
            r2 += bcast_lane(f2, g) * w;
        }
        float a = atomAcc[n * FDIM + f] + (f0 * r0 + f1 * r1 + f2 * r2);
        float s = a;
#pragma unroll
        for (int off = 32; off >= 1; off >>= 1) s += __shfl_xor(s, off, 64);
        const float mu = s * (1.0f / 64.0f);
        const float d = a - mu;
        float v = d * d;
#pragma unroll
        for (int off = 32; off >= 1; off >>= 1) v += __shfl_xor(v, off, 64);
        v *= (1.0f / 64.0f);
        atomAcc[n * FDIM + f] = d * rsqrtf(v + LN_EPS) * gg + bb;
    }
}

extern "C" void kernel_launch(void* const* d_in, const int* in_sizes, int n_in,
                              void* d_out, int out_size, void* d_ws, size_t ws_size,
                              hipStream_t stream)
{
    const float* atom_node  = (const float*)d_in[0];
    const float* force_node = (const float*)d_in[1];
    const float* dir_edge   = (const float*)d_in[2];
    const float* dist_edge  = (const float*)d_in[3];
    const int*   edge_index = (const int*)d_in[4];
    const float* W1   = (const float*)d_in[5];
    const float* b1   = (const float*)d_in[6];
    const float* W2   = (const float*)d_in[7];
    const float* b2   = (const float*)d_in[8];
    const float* We   = (const float*)d_in[9];
    const float* Wq1a = (const float*)d_in[10];
    const float* Wq1b = (const float*)d_in[11];
    const float* Wq2a = (const float*)d_in[12];
    const float* Wq2b = (const float*)d_in[13];
    const float* Wu   = (const float*)d_in[14];
    const float* gamma = (const float*)d_in[15];
    const float* beta  = (const float*)d_in[16];

    float* atomOut  = (float*)d_out;                          // [N,F]
    float* forceOut = (float*)d_out + (size_t)N_NODES * FDIM; // [N,3,F]
    float* mn = (float*)d_ws;                                 // [N,F] scratch

    hipMemcpyAsync(atomOut, atom_node, (size_t)N_NODES * FDIM * sizeof(float),
                   hipMemcpyDeviceToDevice, stream);
    hipMemcpyAsync(forceOut, force_node, (size_t)N_NODES * 3 * FDIM * sizeof(float),
                   hipMemcpyDeviceToDevice, stream);

    dim3 blk4(64, 4);
    dim3 blk16(64, 16);
    node_mlp_kernel<<<512, blk4, 0, stream>>>(atom_node, W1, b1, W2, b2, mn);
    edge_kernel<<<256, blk16, 0, stream>>>(dist_edge, dir_edge, edge_index, mn, We,
                                           Wq1a, Wq1b, Wq2a, Wq2b, force_node,
                                           atomOut, forceOut);
    node_final_kernel<<<512, blk4, 0, stream>>>(Wu, gamma, beta, atomOut, forceOut);
}